// Round 7
// baseline (549.150 us; speedup 1.0000x reference)
//
#include <hip/hip_runtime.h>
#include <stdint.h>
#include <math.h>

#define N_ANCH   1000000
#define PRE_K    6000
#define POST_K   1000
#define WORDS    94            // ceil(6000/64) bit-words per row
#define WPAD     96            // padded row stride (u64) -> 768B, 16B-aligned
#define ROWS     6016          // WORDS*64
#define W_IMG    1333.0f
#define H_IMG    800.0f
#define NBLK     256           // histogram blocks (x1024 threads)

// radix sort config (single block)
#define NS       7168          // sort capacity (112 tiles of 64)
#define TILES    112
#define TPW      7             // tiles per wave (16 waves)
#define PASSES   13            // 13 x 4 bits = 52 = 32-bit key + 20-bit idx

// ws layout (bytes)
#define OFF_KEYS   0x000000u   // u32[1e6]
#define OFF_HIST1  0x400000u   // u32[4096]
#define OFF_HIST2  0x404000u   // u32[256]
#define OFF_CTRL   0x404400u   // [0]=count [1]=T20 [2]=coarse c [3]=base [4],[5]=done
#define OFF_CAND   0x404500u   // u64[NS] 56 KiB
#define OFF_BOXES  0x413000u   // float4[6016]
#define OFF_VALID  0x42B000u   // u32[6016]
#define OFF_MASK   0x431000u   // u64[6016*WPAD] row-major, ends ~0x898800

__device__ __forceinline__ float ref_exp(float v) {
  return (float)exp((double)v);   // correctly-rounded f32 exp via double
}

__device__ __forceinline__ void decode_box(float ax, float ay, float az, float aw,
                                           float dx, float dy, float dz, float dw,
                                           float& x1, float& y1, float& x2, float& y2,
                                           bool& valid) {
  // bit-exact replica of reference fp32 op order (no FMA contraction)
  float wa = __fsub_rn(az, ax);
  float ha = __fsub_rn(aw, ay);
  float xa = __fadd_rn(ax, __fmul_rn(0.5f, wa));
  float ya = __fadd_rn(ay, __fmul_rn(0.5f, ha));
  float x  = __fadd_rn(__fmul_rn(dx, wa), xa);
  float y  = __fadd_rn(__fmul_rn(dy, ha), ya);
  float w  = __fmul_rn(ref_exp(dz), wa);
  float h  = __fmul_rn(ref_exp(dw), ha);
  float hw = __fmul_rn(0.5f, w);
  float hh = __fmul_rn(0.5f, h);
  x1 = fminf(fmaxf(__fsub_rn(x, hw), 0.0f), W_IMG - 1.0f);
  y1 = fminf(fmaxf(__fsub_rn(y, hh), 0.0f), H_IMG - 1.0f);
  x2 = fminf(fmaxf(__fadd_rn(x, hw), 0.0f), W_IMG - 1.0f);
  y2 = fminf(fmaxf(__fadd_rn(y, hh), 0.0f), H_IMG - 1.0f);
  valid = (__fsub_rn(x2, x1) >= 16.0f) && (__fsub_rn(y2, y1) >= 16.0f);
}

__device__ __forceinline__ uint32_t wave_iscan(uint32_t x, int lane) {
  #pragma unroll
  for (int off = 1; off < 64; off <<= 1) {
    uint32_t u = __shfl_up(x, off, 64);
    if (lane >= off) x += u;
  }
  return x;
}

// ---- K1: decode + key + LDS 12-bit hist, atomic-flush; last block finds coarse cut ----
__global__ void __launch_bounds__(1024) k_score(const float4* __restrict__ anchors,
                                                const float4* __restrict__ deltas,
                                                const float*  __restrict__ logits,
                                                uint32_t* __restrict__ keys,
                                                uint32_t* __restrict__ hist1,
                                                uint32_t* __restrict__ ctrl) {
  __shared__ uint32_t lh[4096];
  __shared__ uint32_t amLast;
  int tid = threadIdx.x;
  int lane = tid & 63;
  for (int b = tid; b < 4096; b += 1024) lh[b] = 0u;
  __syncthreads();
  for (int i = blockIdx.x * 1024 + tid; i < N_ANCH; i += NBLK * 1024) {
    float4 a = anchors[i];
    float4 d = deltas[i];
    float x1, y1, x2, y2; bool valid;
    decode_box(a.x, a.y, a.z, a.w, d.x, d.y, d.z, d.w, x1, y1, x2, y2, valid);
    uint32_t kd;
    if (valid) {
      double xd = (double)logits[i];
      float s = (float)(1.0 / (1.0 + exp(-xd)));
      uint32_t u = __float_as_uint(s);
      kd = 0x7FFFFFFFu & ~u;        // descending-score -> ascending key
    } else {
      kd = 0xFF800000u;             // -inf key (bin 0xFF8)
    }
    keys[i] = kd;
    uint64_t invb = __ballot(!valid);   // aggregate the hot invalid bin
    if (valid) {
      atomicAdd(&lh[kd >> 20], 1u);
    } else if ((invb & ((1ull << lane) - 1ull)) == 0ull) {
      atomicAdd(&lh[0xFF8u], (uint32_t)__popcll((unsigned long long)invb));
    }
  }
  __syncthreads();
  for (int b = tid; b < 4096; b += 1024)
    if (lh[b]) atomicAdd(&hist1[b], lh[b]);
  __threadfence();
  if (tid == 0) amLast = (atomicAdd(&ctrl[4], 1u) == NBLK - 1) ? 1u : 0u;
  __syncthreads();
  if (!amLast) return;
  __threadfence();
  // ---- findcut1 ----
  __shared__ uint32_t part[1024];
  int t = tid;
  uint4 s4 = ((const uint4*)hist1)[t];       // bins 4t..4t+3
  uint32_t tot = s4.x + s4.y + s4.z + s4.w;
  part[t] = tot;
  __syncthreads();
  uint32_t inc = tot;
  for (int off = 1; off < 1024; off <<= 1) {
    uint32_t u = (t >= off) ? part[t - off] : 0u;
    __syncthreads();
    inc += u;
    part[t] = inc;
    __syncthreads();
  }
  uint32_t ex = inc - tot;
  if (ex < PRE_K && inc >= PRE_K) {
    uint32_t run = ex;
    uint32_t binv[4] = { s4.x, s4.y, s4.z, s4.w };
    for (int b = 0; b < 4; b++) {
      if (run + binv[b] >= PRE_K) { ctrl[2] = 4 * t + b; ctrl[3] = run; break; }
      run += binv[b];
    }
  }
  if (t == 1023 && inc < PRE_K) { ctrl[2] = 4095u; ctrl[3] = inc; }
}

// ---- K2: refine next 8 bits in coarse bin; last block finds T20 ----
__global__ void __launch_bounds__(1024) k_hist2(const uint32_t* __restrict__ keys,
                                                uint32_t* __restrict__ ctrl,
                                                uint32_t* __restrict__ hist2) {
  __shared__ uint32_t lh[256];
  __shared__ uint32_t amLast;
  int tid = threadIdx.x;
  if (tid < 256) lh[tid] = 0u;
  __syncthreads();
  uint32_t c = ctrl[2];
  for (int i = blockIdx.x * 1024 + tid; i < N_ANCH; i += NBLK * 1024) {
    uint32_t k = keys[i];
    if ((k >> 20) == c) atomicAdd(&lh[(k >> 12) & 0xFFu], 1u);
  }
  __syncthreads();
  if (tid < 256 && lh[tid]) atomicAdd(&hist2[tid], lh[tid]);
  __threadfence();
  if (tid == 0) amLast = (atomicAdd(&ctrl[5], 1u) == NBLK - 1) ? 1u : 0u;
  __syncthreads();
  if (!amLast) return;
  __threadfence();
  if (tid < 64) {
    int lane = tid;
    uint32_t b0 = hist2[4 * lane], b1 = hist2[4 * lane + 1];
    uint32_t b2 = hist2[4 * lane + 2], b3 = hist2[4 * lane + 3];
    uint32_t tot = b0 + b1 + b2 + b3;
    uint32_t inc = wave_iscan(tot, lane);
    uint32_t base = ctrl[3];
    uint32_t ex = inc - tot;
    if (base + ex < PRE_K && base + inc >= PRE_K) {
      uint32_t run = base + ex;
      uint32_t binv[4] = { b0, b1, b2, b3 };
      for (int b = 0; b < 4; b++) {
        if (run + binv[b] >= PRE_K) { ctrl[1] = (c << 8) | (uint32_t)(4 * lane + b); break; }
        run += binv[b];
      }
    }
    if (lane == 63 && base + inc < PRE_K) ctrl[1] = 0xFFFFFu;  // take everything
  }
}

// ---- K3: compact candidates (key prefix <= T), wave-aggregated atomic ----
__global__ void k_compact(const uint32_t* __restrict__ keys,
                          const uint32_t* __restrict__ ctrl,
                          uint32_t* __restrict__ cnt,
                          uint64_t* __restrict__ cand) {
  int i = blockIdx.x * blockDim.x + threadIdx.x;
  uint32_t T = ctrl[1];
  bool pass = (i < N_ANCH) && ((keys[i] >> 12) <= T);
  uint64_t m = __ballot(pass);
  if (pass) {
    int lane = threadIdx.x & 63;
    int leader = __ffsll((unsigned long long)m) - 1;
    uint32_t base = 0;
    if (lane == leader) base = atomicAdd(cnt, (uint32_t)__popcll((unsigned long long)m));
    base = (uint32_t)__shfl((int)base, leader);
    uint32_t pos = (uint32_t)__popcll((unsigned long long)(m & ((1ull << lane) - 1ull)));
    uint32_t p = base + pos;
    if (p < NS) cand[p] = ((uint64_t)keys[i] << 20) | (uint32_t)i;  // 52-bit packed
  }
}

// ---- K4: single-block LSD radix sort (4-bit x 13) + gather/decode epilogue ----
__global__ void __launch_bounds__(1024) k_sortgather(
    const uint32_t* __restrict__ ctrl,
    const uint64_t* __restrict__ cand,
    const float4* __restrict__ anchors,
    const float4* __restrict__ deltas,
    float4* __restrict__ boxes,
    uint32_t* __restrict__ valid) {
  __shared__ uint64_t buf[NS];            // 56 KiB
  __shared__ uint32_t hist[16 * TILES];   // 7 KiB
  __shared__ uint32_t dtot[16];
  __shared__ uint32_t dbase[16];
  __shared__ uint32_t skipf;
  int tid = threadIdx.x;
  int wave = tid >> 6, lane = tid & 63;
  uint32_t M = ctrl[0]; if (M > NS) M = NS;
  uint32_t T = ctrl[1];
  uint64_t pad = (T >= 0xFFFFFu) ? 0xFFFFFFFFFFFFFull
                                 : ((((uint64_t)T + 1) << 32) | 0xFFFFFFFFull);
  for (int i = tid; i < NS; i += 1024)
    buf[i] = (i < (int)M) ? cand[i] : pad;
  __syncthreads();
  uint64_t lmask_lt = (1ull << lane) - 1ull;

  for (int p = 0; p < PASSES; p++) {
    int shift = 4 * p;
    for (int i = tid; i < 16 * TILES; i += 1024) hist[i] = 0u;
    uint64_t v[TPW]; int dg[TPW]; int rk[TPW];
    #pragma unroll
    for (int k = 0; k < TPW; k++)
      v[k] = buf[(wave * TPW + k) * 64 + lane];
    __syncthreads();
    #pragma unroll
    for (int k = 0; k < TPW; k++) {
      int d = (int)((v[k] >> shift) & 0xF);
      uint64_t m = ~0ull;
      #pragma unroll
      for (int b = 0; b < 4; b++) {
        uint64_t bal = __ballot((d >> b) & 1);
        m &= ((d >> b) & 1) ? bal : ~bal;
      }
      int r = (int)__popcll((unsigned long long)(m & lmask_lt));
      dg[k] = d; rk[k] = r;
      if (r == 0) hist[d * TILES + wave * TPW + k] = (uint32_t)__popcll((unsigned long long)m);
    }
    __syncthreads();
    {
      int d = wave;
      uint32_t c0 = hist[d * TILES + lane];
      uint32_t c1 = (lane < TILES - 64) ? hist[d * TILES + 64 + lane] : 0u;
      uint32_t s0 = wave_iscan(c0, lane);
      uint32_t T0 = (uint32_t)__shfl((int)s0, 63, 64);
      uint32_t s1 = wave_iscan(c1, lane);
      uint32_t T1 = (uint32_t)__shfl((int)s1, 63, 64);
      hist[d * TILES + lane] = s0 - c0;
      if (lane < TILES - 64) hist[d * TILES + 64 + lane] = T0 + (s1 - c1);
      if (lane == 0) dtot[d] = T0 + T1;
    }
    __syncthreads();
    if (wave == 0) {
      uint32_t x = (lane < 16) ? dtot[lane] : 0u;
      uint32_t xs = wave_iscan(x, lane);
      if (lane < 16) dbase[lane] = xs - x;
      if (lane == 0) skipf = 0u;
      if (lane < 16 && x == NS) skipf = 1u;
    }
    __syncthreads();
    if (!skipf) {
      #pragma unroll
      for (int k = 0; k < TPW; k++) {
        uint32_t dst = dbase[dg[k]] + hist[dg[k] * TILES + wave * TPW + k] + (uint32_t)rk[k];
        buf[dst] = v[k];
      }
    }
    __syncthreads();
  }

  for (int r = tid; r < ROWS; r += 1024) {
    if (r >= PRE_K) { boxes[r] = make_float4(0.f, 0.f, 0.f, 0.f); valid[r] = 0u; continue; }
    uint64_t kk = buf[r];
    uint32_t kd = (uint32_t)(kk >> 20);
    if (kk >= pad || kd >= 0xFF800000u) {
      boxes[r] = make_float4(0.f, 0.f, 0.f, 0.f); valid[r] = 0u; continue;
    }
    uint32_t idx = (uint32_t)(kk & 0xFFFFFu);
    float4 a = anchors[idx];
    float4 d = deltas[idx];
    float x1, y1, x2, y2; bool vv;
    decode_box(a.x, a.y, a.z, a.w, d.x, d.y, d.z, d.w, x1, y1, x2, y2, vv);
    boxes[r] = make_float4(x1, y1, x2, y2);
    valid[r] = 1u;
  }
}

// ---- K5: IoU bitmask, row-major mask[row*WPAD + w] ----
__global__ void __launch_bounds__(64) k_iou(const float4* __restrict__ boxes,
                                            uint64_t* __restrict__ mask) {
  int by = blockIdx.y, bx = blockIdx.x;
  if (bx < by) return;               // only words w >= row's group are ever consumed
  __shared__ float4 cb[64];
  int t = threadIdx.x;
  cb[t] = boxes[bx * 64 + t];
  __syncthreads();
  int i = by * 64 + t;
  float4 b = boxes[i];
  float ax1 = b.x, ay1 = b.y, ax2 = b.z, ay2 = b.w;
  float areaA = __fmul_rn(__fsub_rn(ax2, ax1), __fsub_rn(ay2, ay1));
  uint64_t bits = 0;
  for (int c = 0; c < 64; c++) {
    float4 o = cb[c];
    float areaB = __fmul_rn(__fsub_rn(o.z, o.x), __fsub_rn(o.w, o.y));
    float ix1 = fmaxf(ax1, o.x), iy1 = fmaxf(ay1, o.y);
    float ix2 = fminf(ax2, o.z), iy2 = fminf(ay2, o.w);
    float iw = fmaxf(__fsub_rn(ix2, ix1), 0.0f);
    float ih = fmaxf(__fsub_rn(iy2, iy1), 0.0f);
    float inter = __fmul_rn(iw, ih);
    float uni = __fsub_rn(__fadd_rn(areaA, areaB), inter);
    bool sup = (uni > 0.0f) && (__fdiv_rn(inter, uni) > 0.7f);
    bits |= ((uint64_t)sup) << c;
  }
  mask[(size_t)i * WPAD + bx] = bits;
}

// wave-uniform 64-bit broadcast via v_readlane
__device__ __forceinline__ uint64_t bcast64(uint64_t v, int lane) {
  uint32_t lo = (uint32_t)__builtin_amdgcn_readlane((int)(uint32_t)v, lane);
  uint32_t hi = (uint32_t)__builtin_amdgcn_readlane((int)(uint32_t)(v >> 32), lane);
  return ((uint64_t)hi << 32) | lo;
}

#define SLOTS 32

// DMA one mask row (768B used of 96 u64) into an LDS stage row: no dest VGPRs.
__device__ __forceinline__ void dma_row(const uint64_t* rowp, uint64_t* ldsrow, int lane) {
  if (lane < 48)
    __builtin_amdgcn_global_load_lds(
        (const __attribute__((address_space(1))) uint32_t*)(rowp + 2 * lane),
        (__attribute__((address_space(3))) uint32_t*)ldsrow,
        16, 0, 0);
}

// OR staged rows into r0/r1 (clamped index + idempotent OR -> no predication)
__device__ __forceinline__ void commit_rows(const uint64_t (*sbuf)[WPAD], int n,
                                            int w0, int w1, uint64_t& r0, uint64_t& r1) {
  if (n <= 0) return;
  int w1s = (w1 < WORDS) ? w1 : 0;
  uint64_t a0 = 0, a1 = 0;
  for (int jb = 0; jb < n; jb += 8) {
    #pragma unroll
    for (int ji = 0; ji < 8; ji++) {
      int js = jb + ji; js = (js < n) ? js : (n - 1);
      a0 |= sbuf[js][w0];
      a1 |= sbuf[js][w1s];
    }
  }
  r0 |= a0;
  if (w1 < WORDS) r1 |= a1;
}

// ---- K6: sequential NMS; LDS-DMA fold, one-group lookahead via colv2 ----
__global__ void __launch_bounds__(64, 1) k_nms(const uint64_t* __restrict__ mask,
                                               const float4* __restrict__ boxes,
                                               const uint32_t* __restrict__ valid,
                                               float* __restrict__ out) {
  __shared__ uint64_t stage[2][SLOTS][WPAD] __attribute__((aligned(16)));  // 48 KiB
  __shared__ uint32_t list[1024];
  int lane = threadIdx.x;
  int w0 = lane, w1 = lane + 64;
  uint64_t r0 = 0, r1 = 0;      // removed-bit words (lane owns w0, w1); folds <= g-2
  uint64_t cur_next = 0;        // word-(g) bits contributed by rows kept in group g-1
  int cnt = 0, pendN = 0;
  uint64_t colv  = mask[(size_t)lane * WPAD + 0];   // row lane's word 0
  uint64_t colv2 = mask[(size_t)lane * WPAD + 1];   // row lane's word 1
  uint32_t vf = valid[lane];
  for (int g = 0; g < WORDS; g++) {
    int base = g * 64;
    int ping = g & 1;
    uint64_t cur = ((g < 64) ? bcast64(r0, g) : bcast64(r1, g - 64)) | cur_next;
    uint64_t vmask = __ballot(vf != 0u);
    uint64_t alive = vmask & ~cur;
    uint64_t keptmask = 0;
    cur_next = 0;
    while (alive) {                                  // serial decision chain
      int r = __ffsll((unsigned long long)alive) - 1;
      keptmask |= 1ull << r;
      if (lane == 0) list[cnt] = (uint32_t)(base + r);
      cnt++;
      if (cnt >= POST_K) break;
      alive &= ~bcast64(colv, r);                    // in-group suppression
      alive &= ~(1ull << r);
      cur_next |= bcast64(colv2, r);                 // row r's word g+1 -> next group
    }
    if (cnt >= POST_K) break;
    // commit previous group's staged rows (DMAs had a full group to land)
    __builtin_amdgcn_s_waitcnt(0xF70);               // vmcnt(0)
    commit_rows(stage[ping ^ 1], pendN, w0, w1, r0, r1);
    // issue DMAs for this group's kept rows
    uint64_t kml = keptmask;
    int slot = 0;
    while (kml) {
      if (slot == SLOTS) {                           // rare overflow: drain in place
        __builtin_amdgcn_s_waitcnt(0xF70);
        commit_rows(stage[ping], SLOTS, w0, w1, r0, r1);
        slot = 0;
      }
      int r = __ffsll((unsigned long long)kml) - 1;
      kml &= kml - 1;
      dma_row(mask + (size_t)(base + r) * WPAD, &stage[ping][slot][0], lane);
      slot++;
    }
    pendN = slot;
    // prefetch next group's column words + validity
    if (g + 1 < WORDS) {
      const uint64_t* nrow = mask + (size_t)(base + 64 + lane) * WPAD;
      colv  = nrow[g + 1];
      colv2 = nrow[g + 2];                           // g+2 <= 95 < WPAD, safe
      vf = valid[base + 64 + lane];
    }
  }
  __syncthreads();
  float4* outv = (float4*)out;
  for (int k = lane; k < POST_K; k += 64)
    outv[k] = (k < cnt) ? boxes[list[k]] : make_float4(0.f, 0.f, 0.f, 0.f);
}

extern "C" void kernel_launch(void* const* d_in, const int* in_sizes, int n_in,
                              void* d_out, int out_size, void* d_ws, size_t ws_size,
                              hipStream_t stream) {
  const float4* anchors = (const float4*)d_in[1];
  const float4* deltas  = (const float4*)d_in[2];
  const float*  logits  = (const float*)d_in[3];
  char* w = (char*)d_ws;
  uint32_t* keys  = (uint32_t*)(w + OFF_KEYS);
  uint32_t* hist1 = (uint32_t*)(w + OFF_HIST1);
  uint32_t* hist2 = (uint32_t*)(w + OFF_HIST2);
  uint32_t* ctrl  = (uint32_t*)(w + OFF_CTRL);
  uint64_t* cand  = (uint64_t*)(w + OFF_CAND);
  float4*   boxes = (float4*)(w + OFF_BOXES);
  uint32_t* valid = (uint32_t*)(w + OFF_VALID);
  uint64_t* mask  = (uint64_t*)(w + OFF_MASK);
  float*    out   = (float*)d_out;

  // zero hist1+hist2+ctrl (contiguous region)
  hipMemsetAsync(w + OFF_HIST1, 0, 0x4600, stream);

  k_score<<<NBLK, 1024, 0, stream>>>(anchors, deltas, logits, keys, hist1, ctrl);
  k_hist2<<<NBLK, 1024, 0, stream>>>(keys, ctrl, hist2);
  k_compact<<<(N_ANCH + 255) / 256, 256, 0, stream>>>(keys, ctrl, &ctrl[0], cand);
  k_sortgather<<<1, 1024, 0, stream>>>(ctrl, cand, anchors, deltas, boxes, valid);
  k_iou<<<dim3(WORDS, WORDS), 64, 0, stream>>>(boxes, mask);
  k_nms<<<1, 64, 0, stream>>>(mask, boxes, valid, out);
}

// Round 8
// 486.102 us; speedup vs baseline: 1.1297x; 1.1297x over previous
//
#include <hip/hip_runtime.h>
#include <stdint.h>
#include <math.h>

#define N_ANCH   1000000
#define PRE_K    6000
#define POST_K   1000
#define WORDS    94            // ceil(6000/64) bit-words per row
#define WPAD     96            // padded row stride (u64) -> 768B, 16B-aligned
#define ROWS     6016          // WORDS*64
#define W_IMG    1333.0f
#define H_IMG    800.0f
#define NBLK1    64            // histogram blocks (x1024 threads)

// radix sort config (single block)
#define NS       7168          // sort capacity (112 tiles of 64)
#define TILES    112
#define TPW      7             // tiles per wave (16 waves)
#define PASSES   13            // 13 x 4 bits = 52 = 32-bit key + 20-bit idx

// ws layout (bytes). keys and maskT ALIAS (disjoint lifetimes: keys dead after
// k_compact; maskT written by k_iou afterwards). part1 overlaps maskT tail
// (part1 dead after k_score's last block, long before k_iou).
#define OFF_KEYS   0x000000u   // u32[1e6]            (4,000,000 B)
#define OFF_MASKT  0x000000u   // u64[WORDS*ROWS]     (4,521,984 B) -> 0x450000
#define OFF_PART1  0x3D1000u   // u32[NBLK1*4096] 1 MiB -> 0x4D1000
#define OFF_PART2  0x4D1000u   // u32[NBLK1*256] 64 KiB -> 0x4E1000
#define OFF_CTRL   0x4E1000u   // [0]=count [1]=T20 [2]=coarse c [3]=base [4],[5]=done
#define OFF_CAND   0x4E1100u   // u64[NS] 56 KiB
#define OFF_BOXES  0x4F0000u   // float4[6016]
#define OFF_VALID  0x508000u   // u32[6016]
#define OFF_MASK   0x510000u   // u64[6016*WPAD] row-major -> ends 0x978000 (~9.9MB)

#define AS1 __attribute__((address_space(1)))
#define AS3 __attribute__((address_space(3)))

__device__ __forceinline__ float ref_exp(float v) {
  return (float)exp((double)v);   // correctly-rounded f32 exp via double
}

__device__ __forceinline__ void decode_box(float ax, float ay, float az, float aw,
                                           float dx, float dy, float dz, float dw,
                                           float& x1, float& y1, float& x2, float& y2,
                                           bool& valid) {
  // bit-exact replica of reference fp32 op order (no FMA contraction)
  float wa = __fsub_rn(az, ax);
  float ha = __fsub_rn(aw, ay);
  float xa = __fadd_rn(ax, __fmul_rn(0.5f, wa));
  float ya = __fadd_rn(ay, __fmul_rn(0.5f, ha));
  float x  = __fadd_rn(__fmul_rn(dx, wa), xa);
  float y  = __fadd_rn(__fmul_rn(dy, ha), ya);
  float w  = __fmul_rn(ref_exp(dz), wa);
  float h  = __fmul_rn(ref_exp(dw), ha);
  float hw = __fmul_rn(0.5f, w);
  float hh = __fmul_rn(0.5f, h);
  x1 = fminf(fmaxf(__fsub_rn(x, hw), 0.0f), W_IMG - 1.0f);
  y1 = fminf(fmaxf(__fsub_rn(y, hh), 0.0f), H_IMG - 1.0f);
  x2 = fminf(fmaxf(__fadd_rn(x, hw), 0.0f), W_IMG - 1.0f);
  y2 = fminf(fmaxf(__fadd_rn(y, hh), 0.0f), H_IMG - 1.0f);
  valid = (__fsub_rn(x2, x1) >= 16.0f) && (__fsub_rn(y2, y1) >= 16.0f);
}

__device__ __forceinline__ uint32_t wave_iscan(uint32_t x, int lane) {
  #pragma unroll
  for (int off = 1; off < 64; off <<= 1) {
    uint32_t u = __shfl_up(x, off, 64);
    if (lane >= off) x += u;
  }
  return x;
}

// ---- K1: decode + score key + 12-bit LDS hist -> per-block partials (round-6 proven) ----
__global__ void __launch_bounds__(1024) k_score(const float4* __restrict__ anchors,
                                                const float4* __restrict__ deltas,
                                                const float*  __restrict__ logits,
                                                uint32_t* __restrict__ keys,
                                                uint32_t* __restrict__ part1,
                                                uint32_t* __restrict__ ctrl) {
  __shared__ uint32_t lh[4096];
  __shared__ uint32_t amLast;
  int tid = threadIdx.x;
  int lane = tid & 63;
  for (int b = tid; b < 4096; b += 1024) lh[b] = 0u;
  __syncthreads();
  for (int i = blockIdx.x * 1024 + tid; i < N_ANCH; i += NBLK1 * 1024) {
    float4 a = anchors[i];
    float4 d = deltas[i];
    float x1, y1, x2, y2; bool valid;
    decode_box(a.x, a.y, a.z, a.w, d.x, d.y, d.z, d.w, x1, y1, x2, y2, valid);
    uint32_t kd;
    if (valid) {
      double xd = (double)logits[i];
      float s = (float)(1.0 / (1.0 + exp(-xd)));
      uint32_t u = __float_as_uint(s);
      kd = 0x7FFFFFFFu & ~u;        // descending-score -> ascending key
    } else {
      kd = 0xFF800000u;             // -inf key (bin 0xFF8)
    }
    keys[i] = kd;
    uint64_t invb = __ballot(!valid);   // aggregate the hot invalid bin
    if (valid) {
      atomicAdd(&lh[kd >> 20], 1u);
    } else if ((invb & ((1ull << lane) - 1ull)) == 0ull) {
      atomicAdd(&lh[0xFF8u], (uint32_t)__popcll((unsigned long long)invb));
    }
  }
  __syncthreads();
  for (int b = tid; b < 4096; b += 1024)
    part1[blockIdx.x * 4096 + b] = lh[b];
  __threadfence();
  if (tid == 0) amLast = (atomicAdd(&ctrl[4], 1u) == NBLK1 - 1) ? 1u : 0u;
  __syncthreads();
  if (!amLast) return;
  __threadfence();
  // ---- findcut1 (this block only) ----
  __shared__ uint32_t part[1024];
  int t = tid;
  uint4 s4 = make_uint4(0u, 0u, 0u, 0u);     // thread t owns bins 4t..4t+3
  const uint4* p4 = (const uint4*)part1;
  for (int k = 0; k < NBLK1; k++) {
    uint4 q = p4[k * 1024 + t];
    s4.x += q.x; s4.y += q.y; s4.z += q.z; s4.w += q.w;
  }
  uint32_t tot = s4.x + s4.y + s4.z + s4.w;
  part[t] = tot;
  __syncthreads();
  uint32_t inc = tot;
  for (int off = 1; off < 1024; off <<= 1) {
    uint32_t u = (t >= off) ? part[t - off] : 0u;
    __syncthreads();
    inc += u;
    part[t] = inc;
    __syncthreads();
  }
  uint32_t ex = inc - tot;
  if (ex < PRE_K && inc >= PRE_K) {
    uint32_t run = ex;
    uint32_t binv[4] = { s4.x, s4.y, s4.z, s4.w };
    for (int b = 0; b < 4; b++) {
      if (run + binv[b] >= PRE_K) { ctrl[2] = 4 * t + b; ctrl[3] = run; break; }
      run += binv[b];
    }
  }
  if (t == 1023 && inc < PRE_K) { ctrl[2] = 4095u; ctrl[3] = inc; }
}

// ---- K2: refine next 8 bits in coarse bin; last block finds T20 (round-6 proven) ----
__global__ void __launch_bounds__(1024) k_hist2(const uint32_t* __restrict__ keys,
                                                uint32_t* __restrict__ ctrl,
                                                uint32_t* __restrict__ part2) {
  __shared__ uint32_t lh[256];
  __shared__ uint32_t amLast;
  int tid = threadIdx.x;
  if (tid < 256) lh[tid] = 0u;
  __syncthreads();
  uint32_t c = ctrl[2];
  for (int i = blockIdx.x * 1024 + tid; i < N_ANCH; i += NBLK1 * 1024) {
    uint32_t k = keys[i];
    if ((k >> 20) == c) atomicAdd(&lh[(k >> 12) & 0xFFu], 1u);
  }
  __syncthreads();
  if (tid < 256) part2[blockIdx.x * 256 + tid] = lh[tid];
  __threadfence();
  if (tid == 0) amLast = (atomicAdd(&ctrl[5], 1u) == NBLK1 - 1) ? 1u : 0u;
  __syncthreads();
  if (!amLast) return;
  __threadfence();
  if (tid < 64) {
    int lane = tid;
    uint32_t b0 = 0, b1 = 0, b2 = 0, b3 = 0;
    for (int k = 0; k < NBLK1; k++) {
      const uint32_t* p = part2 + k * 256 + 4 * lane;
      b0 += p[0]; b1 += p[1]; b2 += p[2]; b3 += p[3];
    }
    uint32_t tot = b0 + b1 + b2 + b3;
    uint32_t inc = wave_iscan(tot, lane);
    uint32_t base = ctrl[3];
    uint32_t ex = inc - tot;
    if (base + ex < PRE_K && base + inc >= PRE_K) {
      uint32_t run = base + ex;
      uint32_t binv[4] = { b0, b1, b2, b3 };
      for (int b = 0; b < 4; b++) {
        if (run + binv[b] >= PRE_K) { ctrl[1] = (c << 8) | (uint32_t)(4 * lane + b); break; }
        run += binv[b];
      }
    }
    if (lane == 63 && base + inc < PRE_K) ctrl[1] = 0xFFFFFu;  // take everything
  }
}

// ---- K3: compact candidates (key prefix <= T), wave-aggregated atomic ----
__global__ void k_compact(const uint32_t* __restrict__ keys,
                          const uint32_t* __restrict__ ctrl,
                          uint32_t* __restrict__ cnt,
                          uint64_t* __restrict__ cand) {
  int i = blockIdx.x * blockDim.x + threadIdx.x;
  uint32_t T = ctrl[1];
  bool pass = (i < N_ANCH) && ((keys[i] >> 12) <= T);
  uint64_t m = __ballot(pass);
  if (pass) {
    int lane = threadIdx.x & 63;
    int leader = __ffsll((unsigned long long)m) - 1;
    uint32_t base = 0;
    if (lane == leader) base = atomicAdd(cnt, (uint32_t)__popcll((unsigned long long)m));
    base = (uint32_t)__shfl((int)base, leader);
    uint32_t pos = (uint32_t)__popcll((unsigned long long)(m & ((1ull << lane) - 1ull)));
    uint32_t p = base + pos;
    if (p < NS) cand[p] = ((uint64_t)keys[i] << 20) | (uint32_t)i;  // 52-bit packed
  }
}

// ---- K4: single-block LSD radix sort (4-bit x 13) + gather/decode epilogue ----
__global__ void __launch_bounds__(1024) k_sortgather(
    const uint32_t* __restrict__ ctrl,
    const uint64_t* __restrict__ cand,
    const float4* __restrict__ anchors,
    const float4* __restrict__ deltas,
    float4* __restrict__ boxes,
    uint32_t* __restrict__ valid) {
  __shared__ uint64_t buf[NS];            // 56 KiB
  __shared__ uint32_t hist[16 * TILES];   // 7 KiB
  __shared__ uint32_t dtot[16];
  __shared__ uint32_t dbase[16];
  __shared__ uint32_t skipf;
  int tid = threadIdx.x;
  int wave = tid >> 6, lane = tid & 63;
  uint32_t M = ctrl[0]; if (M > NS) M = NS;
  uint32_t T = ctrl[1];
  uint64_t pad = (T >= 0xFFFFFu) ? 0xFFFFFFFFFFFFFull
                                 : ((((uint64_t)T + 1) << 32) | 0xFFFFFFFFull);
  for (int i = tid; i < NS; i += 1024)
    buf[i] = (i < (int)M) ? cand[i] : pad;
  __syncthreads();
  uint64_t lmask_lt = (1ull << lane) - 1ull;

  for (int p = 0; p < PASSES; p++) {
    int shift = 4 * p;
    for (int i = tid; i < 16 * TILES; i += 1024) hist[i] = 0u;
    uint64_t v[TPW]; int dg[TPW]; int rk[TPW];
    #pragma unroll
    for (int k = 0; k < TPW; k++)
      v[k] = buf[(wave * TPW + k) * 64 + lane];
    __syncthreads();
    #pragma unroll
    for (int k = 0; k < TPW; k++) {
      int d = (int)((v[k] >> shift) & 0xF);
      uint64_t m = ~0ull;
      #pragma unroll
      for (int b = 0; b < 4; b++) {
        uint64_t bal = __ballot((d >> b) & 1);
        m &= ((d >> b) & 1) ? bal : ~bal;
      }
      int r = (int)__popcll((unsigned long long)(m & lmask_lt));
      dg[k] = d; rk[k] = r;
      if (r == 0) hist[d * TILES + wave * TPW + k] = (uint32_t)__popcll((unsigned long long)m);
    }
    __syncthreads();
    {
      int d = wave;
      uint32_t c0 = hist[d * TILES + lane];
      uint32_t c1 = (lane < TILES - 64) ? hist[d * TILES + 64 + lane] : 0u;
      uint32_t s0 = wave_iscan(c0, lane);
      uint32_t T0 = (uint32_t)__shfl((int)s0, 63, 64);
      uint32_t s1 = wave_iscan(c1, lane);
      uint32_t T1 = (uint32_t)__shfl((int)s1, 63, 64);
      hist[d * TILES + lane] = s0 - c0;
      if (lane < TILES - 64) hist[d * TILES + 64 + lane] = T0 + (s1 - c1);
      if (lane == 0) dtot[d] = T0 + T1;
    }
    __syncthreads();
    if (wave == 0) {
      uint32_t x = (lane < 16) ? dtot[lane] : 0u;
      uint32_t xs = wave_iscan(x, lane);
      if (lane < 16) dbase[lane] = xs - x;
      if (lane == 0) skipf = 0u;
      if (lane < 16 && x == NS) skipf = 1u;
    }
    __syncthreads();
    if (!skipf) {
      #pragma unroll
      for (int k = 0; k < TPW; k++) {
        uint32_t dst = dbase[dg[k]] + hist[dg[k] * TILES + wave * TPW + k] + (uint32_t)rk[k];
        buf[dst] = v[k];
      }
    }
    __syncthreads();
  }

  for (int r = tid; r < ROWS; r += 1024) {
    if (r >= PRE_K) { boxes[r] = make_float4(0.f, 0.f, 0.f, 0.f); valid[r] = 0u; continue; }
    uint64_t kk = buf[r];
    uint32_t kd = (uint32_t)(kk >> 20);
    if (kk >= pad || kd >= 0xFF800000u) {
      boxes[r] = make_float4(0.f, 0.f, 0.f, 0.f); valid[r] = 0u; continue;
    }
    uint32_t idx = (uint32_t)(kk & 0xFFFFFu);
    float4 a = anchors[idx];
    float4 d = deltas[idx];
    float x1, y1, x2, y2; bool vv;
    decode_box(a.x, a.y, a.z, a.w, d.x, d.y, d.z, d.w, x1, y1, x2, y2, vv);
    boxes[r] = make_float4(x1, y1, x2, y2);
    valid[r] = 1u;
  }
}

// ---- K5: IoU bitmask, DUAL layout: row-major mask[row*WPAD+w] + maskT[w*ROWS+row] ----
__global__ void __launch_bounds__(64) k_iou(const float4* __restrict__ boxes,
                                            uint64_t* __restrict__ mask,
                                            uint64_t* __restrict__ maskT) {
  int by = blockIdx.y, bx = blockIdx.x;
  if (bx < by) return;               // only words w >= row's group are ever consumed
  __shared__ float4 cb[64];
  int t = threadIdx.x;
  cb[t] = boxes[bx * 64 + t];
  __syncthreads();
  int i = by * 64 + t;
  float4 b = boxes[i];
  float ax1 = b.x, ay1 = b.y, ax2 = b.z, ay2 = b.w;
  float areaA = __fmul_rn(__fsub_rn(ax2, ax1), __fsub_rn(ay2, ay1));
  uint64_t bits = 0;
  for (int c = 0; c < 64; c++) {
    float4 o = cb[c];
    float areaB = __fmul_rn(__fsub_rn(o.z, o.x), __fsub_rn(o.w, o.y));
    float ix1 = fmaxf(ax1, o.x), iy1 = fmaxf(ay1, o.y);
    float ix2 = fminf(ax2, o.z), iy2 = fminf(ay2, o.w);
    float iw = fmaxf(__fsub_rn(ix2, ix1), 0.0f);
    float ih = fmaxf(__fsub_rn(iy2, iy1), 0.0f);
    float inter = __fmul_rn(iw, ih);
    float uni = __fsub_rn(__fadd_rn(areaA, areaB), inter);
    bool sup = (uni > 0.0f) && (__fdiv_rn(inter, uni) > 0.7f);
    bits |= ((uint64_t)sup) << c;
  }
  mask[(size_t)i * WPAD + bx] = bits;          // row-major (fold DMA source)
  maskT[(size_t)bx * ROWS + i] = bits;         // transposed (column DMA source)
}

// wave-uniform 64-bit broadcast via v_readlane
__device__ __forceinline__ uint64_t bcast64(uint64_t v, int lane) {
  uint32_t lo = (uint32_t)__builtin_amdgcn_readlane((int)(uint32_t)v, lane);
  uint32_t hi = (uint32_t)__builtin_amdgcn_readlane((int)(uint32_t)(v >> 32), lane);
  return ((uint64_t)hi << 32) | lo;
}

#define F_PAD 16   // fold DMA instructions per group (padded -> static vmcnt)

// one mask row (768B) -> LDS stage row: lanes 0..47 x 16B
__device__ __forceinline__ void dma_row(const uint64_t* rowp, uint64_t* ldsrow, int lane) {
  if (lane < 48)
    __builtin_amdgcn_global_load_lds((const AS1 uint32_t*)(rowp + 2 * lane),
                                     (AS3 uint32_t*)ldsrow, 16, 0, 0);
}
// one column vector (64 u64 contiguous, 512B): lanes 0..31 x 16B
__device__ __forceinline__ void dma_col(const uint64_t* src, uint64_t* lds, int lane) {
  if (lane < 32)
    __builtin_amdgcn_global_load_lds((const AS1 uint32_t*)(src + 2 * lane),
                                     (AS3 uint32_t*)lds, 16, 0, 0);
}
// 64 u32 validity flags (256B): 64 lanes x 4B
__device__ __forceinline__ void dma_vf(const uint32_t* src, uint32_t* lds, int lane) {
  __builtin_amdgcn_global_load_lds((const AS1 uint32_t*)(src + lane),
                                   (AS3 uint32_t*)lds, 4, 0, 0);
}

// OR staged rows into r0/r1 (clamped index + idempotent OR -> no predication)
__device__ __forceinline__ void commit_rows(const uint64_t (*sbuf)[WPAD], int n,
                                            int w0, int w1, uint64_t& r0, uint64_t& r1) {
  if (n <= 0) return;
  int w1s = (w1 < WORDS) ? w1 : 0;
  uint64_t a0 = 0, a1 = 0;
  for (int jb = 0; jb < n; jb += 8) {
    #pragma unroll
    for (int ji = 0; ji < 8; ji++) {
      int js = jb + ji; js = (js < n) ? js : (n - 1);
      a0 |= sbuf[js][w0];
      a1 |= sbuf[js][w1s];
    }
  }
  r0 |= a0;
  if (w1 < WORDS) r1 |= a1;
}

// ---- K6: sequential NMS; all-DMA loads, static vmcnt(2) decoupling ----
// Per group g: wait vmcnt(2) [fold(g-1) landed; only col(g+1) DMAs may fly],
// commit fold(g-1) from LDS, ds_read colv/vf (DMA'd 2 groups ago), scan,
// then issue exactly F_PAD fold DMAs (dummy-padded) + 2 col/vf DMAs for g+2.
// No VGPR global loads in the loop -> no compiler vmem waits.
__global__ void __launch_bounds__(64, 1) k_nms(const uint64_t* __restrict__ mask,
                                               const uint64_t* __restrict__ maskT,
                                               const float4* __restrict__ boxes,
                                               const uint32_t* __restrict__ valid,
                                               float* __restrict__ out) {
  __shared__ uint64_t fstage[F_PAD][WPAD] __attribute__((aligned(16)));  // 12 KiB
  __shared__ uint64_t cstage[2][64] __attribute__((aligned(16)));        // 1 KiB
  __shared__ uint32_t vstage[2][64] __attribute__((aligned(16)));
  __shared__ uint32_t list[1024];
  int lane = threadIdx.x;
  int w0 = lane, w1 = lane + 64;
  uint64_t r0 = 0, r1 = 0;      // removed-bit words (lane owns w0, w1)
  int cnt = 0, pendN = 0;
  // preload col/vf for groups 0 and 1
  dma_col(maskT + 0 * ROWS + 0,  &cstage[0][0], lane);
  dma_vf (valid + 0,             &vstage[0][0], lane);
  dma_col(maskT + 1 * (size_t)ROWS + 64, &cstage[1][0], lane);
  dma_vf (valid + 64,            &vstage[1][0], lane);
  __builtin_amdgcn_s_waitcnt(0xF70);   // vmcnt(0)
  for (int g = 0; g < WORDS; g++) {
    int base = g * 64;
    if (g > 0) {
      __builtin_amdgcn_s_waitcnt(0xF72);          // vmcnt(2): fold(g-1) landed
      commit_rows(fstage, pendN, w0, w1, r0, r1); // removed bits through g-1
    }
    uint64_t colv = cstage[g & 1][lane];          // ds_read (lgkmcnt, cheap)
    uint32_t vf   = vstage[g & 1][lane];
    uint64_t cur = (g < 64) ? bcast64(r0, g) : bcast64(r1, g - 64);
    uint64_t vmask = __ballot(vf != 0u);
    uint64_t alive = vmask & ~cur;
    uint64_t keptmask = 0;
    while (alive) {                               // serial decision chain
      int r = __ffsll((unsigned long long)alive) - 1;
      keptmask |= 1ull << r;
      if (lane == 0) list[cnt] = (uint32_t)(base + r);
      cnt++;
      if (cnt >= POST_K) break;
      alive &= ~bcast64(colv, r);                 // in-group suppression
      alive &= ~(1ull << r);
    }
    if (cnt >= POST_K) break;
    // issue fold DMAs for kept rows, padded to exactly F_PAD instructions
    uint64_t kml = keptmask;
    int slot = 0;
    while (kml) {
      if (slot == F_PAD) {                        // rare overflow: drain in place
        __builtin_amdgcn_s_waitcnt(0xF70);
        commit_rows(fstage, F_PAD, w0, w1, r0, r1);
        slot = 0;
      }
      int r = __ffsll((unsigned long long)kml) - 1;
      kml &= kml - 1;
      dma_row(mask + (size_t)(base + r) * WPAD, &fstage[slot][0], lane);
      slot++;
    }
    pendN = slot;
    for (int s = slot; s < F_PAD; s++)            // dummies keep count static
      dma_row(mask + (size_t)base * WPAD, &fstage[s][0], lane);
    // issue col/vf for g+2 (clamped dummy at the tail)
    int gg = (g + 2 < WORDS) ? (g + 2) : (WORDS - 1);
    int rb = gg * 64;                             // rb+63 <= 6015
    dma_col(maskT + (size_t)gg * ROWS + rb, &cstage[g & 1][0], lane);
    dma_vf (valid + rb, &vstage[g & 1][0], lane);
  }
  __syncthreads();
  float4* outv = (float4*)out;
  for (int k = lane; k < POST_K; k += 64)
    outv[k] = (k < cnt) ? boxes[list[k]] : make_float4(0.f, 0.f, 0.f, 0.f);
}

extern "C" void kernel_launch(void* const* d_in, const int* in_sizes, int n_in,
                              void* d_out, int out_size, void* d_ws, size_t ws_size,
                              hipStream_t stream) {
  const float4* anchors = (const float4*)d_in[1];
  const float4* deltas  = (const float4*)d_in[2];
  const float*  logits  = (const float*)d_in[3];
  char* w = (char*)d_ws;
  uint32_t* keys  = (uint32_t*)(w + OFF_KEYS);
  uint64_t* maskT = (uint64_t*)(w + OFF_MASKT);
  uint32_t* part1 = (uint32_t*)(w + OFF_PART1);
  uint32_t* part2 = (uint32_t*)(w + OFF_PART2);
  uint32_t* ctrl  = (uint32_t*)(w + OFF_CTRL);
  uint64_t* cand  = (uint64_t*)(w + OFF_CAND);
  float4*   boxes = (float4*)(w + OFF_BOXES);
  uint32_t* valid = (uint32_t*)(w + OFF_VALID);
  uint64_t* mask  = (uint64_t*)(w + OFF_MASK);
  float*    out   = (float*)d_out;

  hipMemsetAsync(w + OFF_CTRL, 0, 256, stream);   // counters only

  k_score<<<NBLK1, 1024, 0, stream>>>(anchors, deltas, logits, keys, part1, ctrl);
  k_hist2<<<NBLK1, 1024, 0, stream>>>(keys, ctrl, part2);
  k_compact<<<(N_ANCH + 255) / 256, 256, 0, stream>>>(keys, ctrl, &ctrl[0], cand);
  k_sortgather<<<1, 1024, 0, stream>>>(ctrl, cand, anchors, deltas, boxes, valid);
  k_iou<<<dim3(WORDS, WORDS), 64, 0, stream>>>(boxes, mask, maskT);
  k_nms<<<1, 64, 0, stream>>>(mask, maskT, boxes, valid, out);
}